// Round 2
// baseline (1675.503 us; speedup 1.0000x reference)
//
#include <hip/hip_runtime.h>
#include <math.h>

namespace {

constexpr int kN = 200;   // nodes
constexpr int kP = 200;   // patterns
constexpr int kT = 9000;  // time
constexpr int kB = 32;    // batch
constexpr int kS = 360;   // pooled length (T/25)
constexpr int kH = 128;   // hidden

// ---------------------------------------------------------------------------
// Workspace layout (bytes):
// 0        meanh   [B*H]   f32  (zeroed)
// 16384    gsums   [2]     f32  (zeroed) [0]=sum np_^2 [1]=sum tp^2
// 16400    compos  [B*P]   f32  (zeroed, atomic sums of pos window-maxima)
// 42000    comneg  [B*P]   f32  (zeroed)
// 67600    diag    [B*P]   f32
// 93200    ssq_tp  [P]     f32
// 94000    t3val   [P*3]   f32
// 96400    t3sign  [P*3]   f32
// 98800    t3idx   [P*3]   i32
// 101200   npmT    [N*P]   f32  (normalized patterns, transposed n-major)
// 261200   inv_rn  [B*T]   f32
// 1413200  posi    [B*P*S] u16
// 6021200  negi    [B*P*S] u16   (total ~10.6 MB)
// ---------------------------------------------------------------------------

__device__ inline float wave_sum(float v) {
#pragma unroll
  for (int off = 32; off >= 1; off >>= 1) v += __shfl_xor(v, off);
  return v;
}

// -------------------- 1. pattern prep (one wave per pattern row) -----------
__global__ __launch_bounds__(64) void k_pattern(
    const float* __restrict__ pat, float* __restrict__ npmT,
    float* __restrict__ t3val, int* __restrict__ t3idx,
    float* __restrict__ t3sign, float* __restrict__ ssq_tp,
    float* __restrict__ gsums) {
  const int p = blockIdx.x, lane = threadIdx.x;
  __shared__ float row[kN];
  float v[4];
  float ssq = 0.f;
#pragma unroll
  for (int j = 0; j < 4; ++j) {
    int n = lane + 64 * j;
    float val = 0.f;
    if (n < kN) {
      float a = pat[p * kN + n];
      val = (n == p) ? 1.0f : tanhf(a);
    }
    v[j] = val;
    ssq += val * val;
  }
  ssq = wave_sum(ssq);
  const float inv = 1.0f / sqrtf(ssq + 1e-9f);
  float ssqn = 0.f;
#pragma unroll
  for (int j = 0; j < 4; ++j) {
    int n = lane + 64 * j;
    if (n < kN) {
      float nv = v[j] * inv;
      npmT[n * kP + p] = nv;   // transposed: n-major for broadcast staging
      row[n] = nv;
      ssqn += nv * nv;
    }
  }
  ssqn = wave_sum(ssqn);
  __syncthreads();
  if (lane == 0) {
    // top-3 of |row|, first-occurrence tie-break (matches jax.lax.top_k)
    float v1 = -1.f, v2 = -1.f, v3 = -1.f;
    int i1 = 0, i2 = 0, i3 = 0;
    for (int n = 0; n < kN; ++n) {
      float a = fabsf(row[n]);
      if (a > v1)      { v3 = v2; i3 = i2; v2 = v1; i2 = i1; v1 = a; i1 = n; }
      else if (a > v2) { v3 = v2; i3 = i2; v2 = a; i2 = n; }
      else if (a > v3) { v3 = a; i3 = n; }
    }
    float a1 = row[i1], a2 = row[i2], a3 = row[i3];
    t3idx[p * 3 + 0] = i1; t3idx[p * 3 + 1] = i2; t3idx[p * 3 + 2] = i3;
    t3val[p * 3 + 0] = a1; t3val[p * 3 + 1] = a2; t3val[p * 3 + 2] = a3;
    t3sign[p * 3 + 0] = (a1 > 0.f) ? 1.f : ((a1 < 0.f) ? -1.f : 0.f);
    t3sign[p * 3 + 1] = (a2 > 0.f) ? 1.f : ((a2 < 0.f) ? -1.f : 0.f);
    t3sign[p * 3 + 2] = (a3 > 0.f) ? 1.f : ((a3 < 0.f) ? -1.f : 0.f);
    float st = a1 * a1 + a2 * a2 + a3 * a3;
    ssq_tp[p] = st;
    atomicAdd(&gsums[0], ssqn);
    atomicAdd(&gsums[1], st);
  }
}

// -------------------- 2. per-(b,t) frame inverse norms ---------------------
__global__ __launch_bounds__(256) void k_rownorm(const float* __restrict__ x,
                                                 float* __restrict__ inv_rn) {
  int idx = blockIdx.x * 256 + threadIdx.x;
  if (idx >= kB * kT) return;
  int b = idx / kT, t = idx % kT;
  const float* xp = x + (size_t)b * kN * kT + t;
  float s0 = 0.f, s1 = 0.f, s2 = 0.f, s3 = 0.f;
  for (int n = 0; n < kN; n += 4) {
    float x0 = xp[(size_t)(n + 0) * kT];
    float x1 = xp[(size_t)(n + 1) * kT];
    float x2 = xp[(size_t)(n + 2) * kT];
    float x3 = xp[(size_t)(n + 3) * kT];
    s0 += x0 * x0; s1 += x1 * x1; s2 += x2 * x2; s3 += x3 * x3;
  }
  float s = (s0 + s1) + (s2 + s3);
  inv_rn[idx] = 1.0f / sqrtf(s + 1e-9f);
}

// -------------------- 3. fused scores GEMM + window-25 max-pool ------------
// grid = b(32) x tchunk(30) x pgroup(2). block = 256 thr = 4 waves.
// wave = 25 patterns x 300 t; lane (0..59) = t-slot of 5 contiguous t.
// thread tile: 25 p x 5 t = 125 fp32 accumulators; per n-step: 9 LDS instr
// for 125 FMAs (vs 27:50 before). Patterns read as wave-uniform broadcast
// b128 (conflict-free); x as b128+b32 from 8-float padded slots.
__global__ __launch_bounds__(256) void k_scores_pool2(
    const float* __restrict__ x, const float* __restrict__ npmT,
    const float* __restrict__ inv_rn,
    unsigned short* __restrict__ posi, unsigned short* __restrict__ negi,
    float* __restrict__ compos, float* __restrict__ comneg) {
  const int bid = blockIdx.x;
  const int pg = bid & 1;
  const int tc = (bid >> 1) % 30;
  const int b  = bid / 60;
  const int t0 = tc * 300;
  const int tid = threadIdx.x;
  const int wid = tid >> 6, lane = tid & 63;

  __shared__ float xs[20 * 64 * 8];   // 40 KB: [n][slot][8] (5 used + 3 pad)
  __shared__ float ps[20 * 4 * 28];   // 8.96 KB: [n][wave][28] (25 used)
  __shared__ float ivs[300];

  for (int i = tid; i < 300; i += 256) ivs[i] = inv_rn[b * kT + t0 + i];

  float acc[125];
#pragma unroll
  for (int i = 0; i < 125; ++i) acc[i] = 0.f;

  const size_t xb = (size_t)b * kN * kT + t0;

  for (int c = 0; c < 10; ++c) {
    __syncthreads();
    for (int i = tid; i < 20 * 300; i += 256) {
      int n = i / 300, tt = i % 300;
      xs[n * 512 + (tt / 5) * 8 + (tt % 5)] =
          x[xb + (size_t)(c * 20 + n) * kT + tt];
    }
    for (int i = tid; i < 20 * 100; i += 256) {
      int n = i / 100, pp = i % 100;
      ps[n * 112 + (pp / 25) * 28 + (pp % 25)] =
          npmT[(c * 20 + n) * kP + pg * 100 + pp];
    }
    __syncthreads();
    for (int n = 0; n < 20; ++n) {
      const float4 x4 = *(const float4*)&xs[n * 512 + lane * 8];
      const float xv4 = xs[n * 512 + lane * 8 + 4];
      const float* pr = &ps[n * 112 + wid * 28];
#pragma unroll
      for (int g = 0; g < 6; ++g) {
        const float4 p4 = *(const float4*)&pr[g * 4];
        {
          const float pv = p4.x; const int o = (g * 4 + 0) * 5;
          acc[o+0]=fmaf(pv,x4.x,acc[o+0]); acc[o+1]=fmaf(pv,x4.y,acc[o+1]);
          acc[o+2]=fmaf(pv,x4.z,acc[o+2]); acc[o+3]=fmaf(pv,x4.w,acc[o+3]);
          acc[o+4]=fmaf(pv,xv4,acc[o+4]);
        }
        {
          const float pv = p4.y; const int o = (g * 4 + 1) * 5;
          acc[o+0]=fmaf(pv,x4.x,acc[o+0]); acc[o+1]=fmaf(pv,x4.y,acc[o+1]);
          acc[o+2]=fmaf(pv,x4.z,acc[o+2]); acc[o+3]=fmaf(pv,x4.w,acc[o+3]);
          acc[o+4]=fmaf(pv,xv4,acc[o+4]);
        }
        {
          const float pv = p4.z; const int o = (g * 4 + 2) * 5;
          acc[o+0]=fmaf(pv,x4.x,acc[o+0]); acc[o+1]=fmaf(pv,x4.y,acc[o+1]);
          acc[o+2]=fmaf(pv,x4.z,acc[o+2]); acc[o+3]=fmaf(pv,x4.w,acc[o+3]);
          acc[o+4]=fmaf(pv,xv4,acc[o+4]);
        }
        {
          const float pv = p4.w; const int o = (g * 4 + 3) * 5;
          acc[o+0]=fmaf(pv,x4.x,acc[o+0]); acc[o+1]=fmaf(pv,x4.y,acc[o+1]);
          acc[o+2]=fmaf(pv,x4.z,acc[o+2]); acc[o+3]=fmaf(pv,x4.w,acc[o+3]);
          acc[o+4]=fmaf(pv,xv4,acc[o+4]);
        }
      }
      {
        const float pv = pr[24]; const int o = 24 * 5;
        acc[o+0]=fmaf(pv,x4.x,acc[o+0]); acc[o+1]=fmaf(pv,x4.y,acc[o+1]);
        acc[o+2]=fmaf(pv,x4.z,acc[o+2]); acc[o+3]=fmaf(pv,x4.w,acc[o+3]);
        acc[o+4]=fmaf(pv,xv4,acc[o+4]);
      }
    }
  }

  // ---- fused pooling epilogue: 5-lane merge per 25-t window ----
  if (lane < 60) {
    const int w = lane / 5;      // window within chunk (0..11)
    const int k5 = lane % 5;
    float iv[5];
#pragma unroll
    for (int j = 0; j < 5; ++j) iv[j] = ivs[lane * 5 + j];
    const int sidx = tc * 12 + w;
    const int pwbase = pg * 100 + wid * 25;
#pragma unroll
    for (int pp = 0; pp < 25; ++pp) {
      float mv = -1e30f, nv = 1e30f;
      int mi = 0, ni = 0;
#pragma unroll
      for (int j = 0; j < 5; ++j) {
        float s = acc[pp * 5 + j] * iv[j];
        if (s > mv) { mv = s; mi = lane * 5 + j; }
        if (s < nv) { nv = s; ni = lane * 5 + j; }
      }
      float bmv = -1e30f, bnv = 1e30f;
      int bmi = 0, bni = 0;
#pragma unroll
      for (int k = 0; k < 5; ++k) {  // ascending t: preserves first-idx ties
        float v  = __shfl(mv, w * 5 + k);
        int   vi = __shfl(mi, w * 5 + k);
        float u  = __shfl(nv, w * 5 + k);
        int   ui = __shfl(ni, w * 5 + k);
        if (v > bmv) { bmv = v; bmi = vi; }
        if (u < bnv) { bnv = u; bni = ui; }
      }
      if (k5 == 0) {
        const int p = pwbase + pp;
        const size_t o = (size_t)(b * kP + p) * kS + sidx;
        posi[o] = (unsigned short)(t0 + bmi);
        negi[o] = (unsigned short)(t0 + bni);
        atomicAdd(&compos[b * kP + p], bmv);
        atomicAdd(&comneg[b * kP + p], -bnv);   // max(-s) = -min(s)
      }
    }
  }
}

// -------------------- 4. avg_sel (3 masked cols) + scores2 + diag ----------
// one wave per (b,p); 4 waves per block
__global__ __launch_bounds__(256) void k_avgsel(
    const float* __restrict__ x, const float* __restrict__ inv_rn,
    const unsigned short* __restrict__ posi, const unsigned short* __restrict__ negi,
    const float* __restrict__ compos, const float* __restrict__ comneg,
    const int* __restrict__ t3idx, const float* __restrict__ t3val,
    const float* __restrict__ ssq_tp, float* __restrict__ diag) {
  const int gw = blockIdx.x * 4 + (threadIdx.x >> 6);
  const int lane = threadIdx.x & 63;
  const int b = gw / kP, p = gw % kP;
  const int n0 = t3idx[p * 3 + 0], n1 = t3idx[p * 3 + 1], n2 = t3idx[p * 3 + 2];
  const float* xb = x + (size_t)b * kN * kT;
  const float* ivb = inv_rn + b * kT;
  const size_t base = (size_t)(b * kP + p) * kS;
  float a0 = 0.f, a1 = 0.f, a2 = 0.f;
  for (int s = lane; s < kS; s += 64) {
    int tp_ = posi[base + s], tn_ = negi[base + s];
    float ivp = ivb[tp_], ivn = ivb[tn_];
    a0 += xb[(size_t)n0 * kT + tp_] * ivp - xb[(size_t)n0 * kT + tn_] * ivn;
    a1 += xb[(size_t)n1 * kT + tp_] * ivp - xb[(size_t)n1 * kT + tn_] * ivn;
    a2 += xb[(size_t)n2 * kT + tp_] * ivp - xb[(size_t)n2 * kT + tn_] * ivn;
  }
  a0 = wave_sum(a0); a1 = wave_sum(a1); a2 = wave_sum(a2);
  if (lane == 0) {
    const float c0 = 8.16496580927726f;  // sqrt(200/3)
    float T0 = c0 * a0 / 360.0f / 2.0f;
    float T1 = c0 * a1 / 360.0f / 2.0f;
    float T2 = c0 * a2 / 360.0f / 2.0f;
    float st = T0 * T0 + T1 * T1 + T2 * T2;
    float itf = 1.0f / sqrtf(st + 1e-9f);
    float itp = 1.0f / sqrtf(ssq_tp[p] + 1e-9f);
    float s2 = T0 * itf * (t3val[p * 3 + 0] * itp) +
               T1 * itf * (t3val[p * 3 + 1] * itp) +
               T2 * itf * (t3val[p * 3 + 2] * itp);
    float fs = (compos[b * kP + p] / 360.0f + comneg[b * kP + p] / 360.0f) * 0.5f;
    diag[b * kP + p] = fs + 0.25f * (s2 * 0.12247448713915890f);  // sqrt(3/200)
  }
}

// -------------------- 5. graphs scatter (global atomics, scale folded) -----
__global__ __launch_bounds__(256) void k_graphs_scatter(
    const float* __restrict__ diag, const int* __restrict__ t3idx,
    const float* __restrict__ t3sign, float* __restrict__ gout) {
  const int i = blockIdx.x * 256 + threadIdx.x;
  if (i >= kB * kP) return;
  const int b = i / kP, p = i % kP;
  const float d = diag[i];
  int   ii[3];
  float rr[3];
#pragma unroll
  for (int j = 0; j < 3; ++j) {
    ii[j] = t3idx[p * 3 + j];
    rr[j] = t3sign[p * 3 + j] * (1.0f / 3.0f);
  }
  float* go = gout + (size_t)b * kN * kN;
#pragma unroll
  for (int j = 0; j < 3; ++j)
#pragma unroll
    for (int k = 0; k < 3; ++k) {
      float nd = (ii[j] == ii[k]) ? 1.0f : 3.0f;  // non_diag, /0.6 folded
      atomicAdd(&go[ii[j] * kN + ii[k]], d * rr[j] * rr[k] * nd * (1.0f / 0.6f));
    }
}

// -------------------- 6. classifier: h=relu(g@W1+b1), partial mean ---------
__global__ __launch_bounds__(256) void k_classifier(
    const float* __restrict__ graphs, const float* __restrict__ W1,
    const float* __restrict__ b1, float* __restrict__ meanh) {
  const int b = blockIdx.x / 8, nc = blockIdx.x % 8;
  const int tid = threadIdx.x;
  __shared__ float g[25][kN];
  for (int i = tid; i < 25 * kN; i += 256) {
    int n = i / kN, m = i % kN;
    g[n][m] = graphs[(size_t)b * kN * kN + (size_t)(nc * 25 + n) * kN + m];
  }
  __syncthreads();
  const int hh = tid & 127, grp = tid >> 7;  // 0/1
  const int ns = (grp == 0) ? 0 : 13, ne = (grp == 0) ? 13 : 25;
  float sumh = 0.f;
  for (int n = ns; n < ne; ++n) {
    float acc = b1[hh];
    for (int m = 0; m < kN; ++m) acc = fmaf(g[n][m], W1[m * kH + hh], acc);
    sumh += fmaxf(acc, 0.f);
  }
  atomicAdd(&meanh[b * kH + hh], sumh);
}

// -------------------- 7. head: out = mean_h @ W2 + b2, and norm ------------
__global__ __launch_bounds__(64) void k_final(
    const float* __restrict__ meanh, const float* __restrict__ W2,
    const float* __restrict__ b2, const float* __restrict__ gsums,
    float* __restrict__ out) {
  const int tid = threadIdx.x;
  if (tid < 64) {
    int b = tid >> 1, k = tid & 1;
    float acc = 0.f;
    for (int h = 0; h < kH; ++h) {
      float mv = meanh[b * kH + h] / 200.0f;
      acc = fmaf(mv, W2[h * 2 + k], acc);
    }
    out[b * 2 + k] = acc + b2[k];
  }
  if (tid == 0) {
    float r = 1.0f - sqrtf(gsums[1]) / sqrtf(gsums[0]);
    out[64] = r * r;
  }
}

}  // namespace

extern "C" void kernel_launch(void* const* d_in, const int* in_sizes, int n_in,
                              void* d_out, int out_size, void* d_ws, size_t ws_size,
                              hipStream_t stream) {
  const float* x   = (const float*)d_in[0];
  // d_in[1] = length (always 9000; shapes static)
  const float* pat = (const float*)d_in[2];
  const float* W1  = (const float*)d_in[3];
  const float* b1  = (const float*)d_in[4];
  const float* W2  = (const float*)d_in[5];
  const float* b2  = (const float*)d_in[6];
  float* out = (float*)d_out;

  char* ws = (char*)d_ws;
  float* meanh  = (float*)(ws + 0);
  float* gsums  = (float*)(ws + 16384);
  float* compos = (float*)(ws + 16400);
  float* comneg = (float*)(ws + 42000);
  float* diag   = (float*)(ws + 67600);
  float* ssqtp  = (float*)(ws + 93200);
  float* t3val  = (float*)(ws + 94000);
  float* t3sign = (float*)(ws + 96400);
  int*   t3idx  = (int*)(ws + 98800);
  float* npmT   = (float*)(ws + 101200);
  float* invrn  = (float*)(ws + 261200);
  unsigned short* posi = (unsigned short*)(ws + 1413200);
  unsigned short* negi = (unsigned short*)(ws + 6021200);

  // zero: meanh + gsums + compos + comneg
  hipMemsetAsync(d_ws, 0, 67600, stream);
  // zero graphs output region (built via atomics)
  hipMemsetAsync((char*)d_out + 65 * 4, 0, (size_t)kB * kN * kN * 4, stream);

  k_pattern<<<kP, 64, 0, stream>>>(pat, npmT, t3val, t3idx, t3sign, ssqtp, gsums);
  k_rownorm<<<(kB * kT + 255) / 256, 256, 0, stream>>>(x, invrn);
  k_scores_pool2<<<kB * 30 * 2, 256, 0, stream>>>(x, npmT, invrn, posi, negi,
                                                  compos, comneg);
  k_avgsel<<<(kB * kP) / 4, 256, 0, stream>>>(x, invrn, posi, negi, compos, comneg,
                                              t3idx, t3val, ssqtp, diag);
  k_graphs_scatter<<<(kB * kP + 255) / 256, 256, 0, stream>>>(diag, t3idx, t3sign,
                                                              out + 65);
  k_classifier<<<kB * 8, 256, 0, stream>>>(out + 65, W1, b1, meanh);
  k_final<<<1, 64, 0, stream>>>(meanh, W2, b2, gsums, out);
}

// Round 3
// 954.155 us; speedup vs baseline: 1.7560x; 1.7560x over previous
//
#include <hip/hip_runtime.h>
#include <math.h>

namespace {

constexpr int kN = 200;   // nodes
constexpr int kP = 200;   // patterns
constexpr int kT = 9000;  // time
constexpr int kB = 32;    // batch
constexpr int kS = 360;   // pooled length (T/25)
constexpr int kH = 128;   // hidden

// ---------------------------------------------------------------------------
// Workspace layout (bytes) — all zeroed regions first (one memset 0..144448):
// 0       gsums  [2]      f32 (zeroed)  [0]=sum np_^2  [1]=sum tp^2
// 64      meanh  [B*H]    f32 (zeroed)
// 16448   cpos   [B*P]    f32 (zeroed)  sum of pos window maxima
// 42048   cneg   [B*P]    f32 (zeroed)  sum of neg window maxima
// 67648   asum   [B*P*3]  f32 (zeroed)  fused avg_sel gather sums
// 144448  diag   [B*P]    f32
// 170048  ssq_tp [P]      f32
// 170848  t3val  [P*3]    f32
// 173248  t3sign [P*3]    f32
// 175648  t3idx  [P*3]    i32
// 178048  npm    [P*N]    f32 (normalized patterns, row-major)
// total ~338 KB
// ---------------------------------------------------------------------------

__device__ inline float wave_sum(float v) {
#pragma unroll
  for (int off = 32; off >= 1; off >>= 1) v += __shfl_xor(v, off);
  return v;
}

// -------------------- 1. pattern prep (one wave per pattern row) -----------
__global__ __launch_bounds__(64) void k_pattern(
    const float* __restrict__ pat, float* __restrict__ npm,
    float* __restrict__ t3val, int* __restrict__ t3idx,
    float* __restrict__ t3sign, float* __restrict__ ssq_tp,
    float* __restrict__ gsums) {
  const int p = blockIdx.x, lane = threadIdx.x;
  __shared__ float row[kN];
  float v[4];
  float ssq = 0.f;
#pragma unroll
  for (int j = 0; j < 4; ++j) {
    int n = lane + 64 * j;
    float val = 0.f;
    if (n < kN) {
      float a = pat[p * kN + n];
      val = (n == p) ? 1.0f : tanhf(a);
    }
    v[j] = val;
    ssq += val * val;
  }
  ssq = wave_sum(ssq);
  const float inv = 1.0f / sqrtf(ssq + 1e-9f);
  float ssqn = 0.f;
#pragma unroll
  for (int j = 0; j < 4; ++j) {
    int n = lane + 64 * j;
    if (n < kN) {
      float nv = v[j] * inv;
      npm[p * kN + n] = nv;   // row-major (coalesced ps staging in scores)
      row[n] = nv;
      ssqn += nv * nv;
    }
  }
  ssqn = wave_sum(ssqn);
  __syncthreads();
  if (lane == 0) {
    // top-3 of |row|, first-occurrence tie-break (matches jax.lax.top_k)
    float v1 = -1.f, v2 = -1.f, v3 = -1.f;
    int i1 = 0, i2 = 0, i3 = 0;
    for (int n = 0; n < kN; ++n) {
      float a = fabsf(row[n]);
      if (a > v1)      { v3 = v2; i3 = i2; v2 = v1; i2 = i1; v1 = a; i1 = n; }
      else if (a > v2) { v3 = v2; i3 = i2; v2 = a; i2 = n; }
      else if (a > v3) { v3 = a; i3 = n; }
    }
    float a1 = row[i1], a2 = row[i2], a3 = row[i3];
    t3idx[p * 3 + 0] = i1; t3idx[p * 3 + 1] = i2; t3idx[p * 3 + 2] = i3;
    t3val[p * 3 + 0] = a1; t3val[p * 3 + 1] = a2; t3val[p * 3 + 2] = a3;
    t3sign[p * 3 + 0] = (a1 > 0.f) ? 1.f : ((a1 < 0.f) ? -1.f : 0.f);
    t3sign[p * 3 + 1] = (a2 > 0.f) ? 1.f : ((a2 < 0.f) ? -1.f : 0.f);
    t3sign[p * 3 + 2] = (a3 > 0.f) ? 1.f : ((a3 < 0.f) ? -1.f : 0.f);
    float st = a1 * a1 + a2 * a2 + a3 * a3;
    ssq_tp[p] = st;
    atomicAdd(&gsums[0], ssqn);
    atomicAdd(&gsums[1], st);
  }
}

// -------------------- 2. fused scores GEMM + rownorm + pool + avg_sel ------
// Round-0-proven GEMM core (thread = 25t x 2p, VGPR ~60, no spill).
// block: (b, wchunk of 5 windows = 125 t). 512 threads; tid<500 active,
// thread = (p2 = tid%100, w = tid/100); owns patterns {p2, p2+100}, window w.
// Fused in: (a) ssq[t] accumulated during x staging -> iv = 1/sqrt(ssq+eps)
// (deletes k_rownorm); (b) pooling epilogue gathers the 3 masked x-columns
// at pos/neg argmax t (L2-hot) and LDS-reduces into asum/cpos/cneg
// (deletes k_avgsel and the posi/negi arrays).
__global__ __launch_bounds__(512) void k_scores_fused(
    const float* __restrict__ x, const float* __restrict__ npm,
    const int* __restrict__ t3idx,
    float* __restrict__ asumG, float* __restrict__ cposG,
    float* __restrict__ cnegG) {
  const int bid = blockIdx.x;
  const int b = bid / 72, wc = bid % 72;
  const int t0 = wc * 125;
  __shared__ float ps[kP * 51];    // 40.8 KB np_ chunk, pitch 51
  __shared__ float xs[50 * 140];   // 28 KB x chunk, 5 windows padded to 28
  __shared__ float ssq[128];       // per-t sum of squares (125 used)
  __shared__ float asumL[kP * 3];
  __shared__ float cposL[kP];
  __shared__ float cnegL[kP];
  __shared__ int   t3iL[kP * 3];
  const int tid = threadIdx.x;
  const int p2 = tid % 100, w = tid / 100;
  const bool active = tid < 500;

  // init LDS accumulators + stage t3idx
  for (int i = tid; i < kP * 3; i += 512) { asumL[i] = 0.f; t3iL[i] = t3idx[i]; }
  for (int i = tid; i < kP; i += 512) { cposL[i] = 0.f; cnegL[i] = 0.f; }
  for (int i = tid; i < 128; i += 512) ssq[i] = 0.f;

  float accA[25], accB[25];
#pragma unroll
  for (int t = 0; t < 25; ++t) { accA[t] = 0.f; accB[t] = 0.f; }
  const size_t xbase = (size_t)b * kN * kT;
  const size_t xb = xbase + t0;

  for (int nc = 0; nc < 4; ++nc) {   // 4 chunks of 50 n
    __syncthreads();
    for (int i = tid; i < kP * 50; i += 512) {
      int p = i / 50, n = i % 50;
      ps[p * 51 + n] = npm[p * kN + nc * 50 + n];
    }
    for (int i = tid; i < 50 * 125; i += 512) {
      int n = i / 125, tt = i % 125;
      float v = x[xb + (size_t)(nc * 50 + n) * kT + tt];
      xs[n * 140 + (tt / 25) * 28 + (tt % 25)] = v;
      atomicAdd(&ssq[tt], v * v);   // fused rownorm (lanes hit distinct t)
    }
    __syncthreads();
    if (active) {
      for (int n = 0; n < 50; ++n) {
        float va = ps[p2 * 51 + n];
        float vb = ps[(p2 + 100) * 51 + n];
        const float* xr = &xs[n * 140 + w * 28];
#pragma unroll
        for (int t = 0; t < 25; ++t) {
          float xv = xr[t];
          accA[t] = fmaf(va, xv, accA[t]);
          accB[t] = fmaf(vb, xv, accB[t]);
        }
      }
    }
  }

  // ---- fused epilogue: pooling + masked-column gathers ----
  if (active) {
    const int tg0 = t0 + w * 25;
    float iv[25];
#pragma unroll
    for (int t = 0; t < 25; ++t) iv[t] = 1.0f / sqrtf(ssq[w * 25 + t] + 1e-9f);

#define DO_HALF(ACC, PIDX)                                                    \
    {                                                                         \
      const int P_ = (PIDX);                                                  \
      float bmv = -1e30f, bnv = 1e30f, ivp = 0.f, ivn = 0.f;                  \
      int bmi = 0, bni = 0;                                                   \
      _Pragma("unroll")                                                       \
      for (int t = 0; t < 25; ++t) {                                          \
        float s = ACC[t] * iv[t];                                             \
        if (s > bmv) { bmv = s; bmi = t; ivp = iv[t]; }                       \
        if (s < bnv) { bnv = s; bni = t; ivn = iv[t]; }                       \
      }                                                                       \
      atomicAdd(&cposL[P_], bmv);                                             \
      atomicAdd(&cnegL[P_], -bnv);   /* max(-s) = -min(s) */                  \
      const int gp = tg0 + bmi, gn = tg0 + bni;                               \
      _Pragma("unroll")                                                       \
      for (int j = 0; j < 3; ++j) {                                           \
        int nj = t3iL[P_ * 3 + j];                                            \
        float xpv = x[xbase + (size_t)nj * kT + gp];                          \
        float xnv = x[xbase + (size_t)nj * kT + gn];                          \
        atomicAdd(&asumL[P_ * 3 + j], xpv * ivp - xnv * ivn);                 \
      }                                                                       \
    }

    DO_HALF(accA, p2)
    DO_HALF(accB, p2 + 100)
#undef DO_HALF
  }

  __syncthreads();
  // flush block-local accumulators to global
  for (int i = tid; i < kP * 5; i += 512) {
    if (i < kP * 3)           atomicAdd(&asumG[b * kP * 3 + i], asumL[i]);
    else if (i < kP * 4)      atomicAdd(&cposG[b * kP + (i - kP * 3)], cposL[i - kP * 3]);
    else                      atomicAdd(&cnegG[b * kP + (i - kP * 4)], cnegL[i - kP * 4]);
  }
}

// -------------------- 3. per-(b,p) diag scalar math ------------------------
__global__ __launch_bounds__(256) void k_diag(
    const float* __restrict__ asumG, const float* __restrict__ cposG,
    const float* __restrict__ cnegG, const float* __restrict__ t3val,
    const float* __restrict__ ssq_tp, float* __restrict__ diag) {
  const int i = blockIdx.x * 256 + threadIdx.x;
  if (i >= kB * kP) return;
  const int p = i % kP;
  const float c0 = 8.16496580927726f;  // sqrt(200/3)
  float a0 = asumG[i * 3 + 0], a1 = asumG[i * 3 + 1], a2 = asumG[i * 3 + 2];
  float T0 = c0 * a0 / 360.0f / 2.0f;
  float T1 = c0 * a1 / 360.0f / 2.0f;
  float T2 = c0 * a2 / 360.0f / 2.0f;
  float st = T0 * T0 + T1 * T1 + T2 * T2;
  float itf = 1.0f / sqrtf(st + 1e-9f);
  float itp = 1.0f / sqrtf(ssq_tp[p] + 1e-9f);
  float s2 = T0 * itf * (t3val[p * 3 + 0] * itp) +
             T1 * itf * (t3val[p * 3 + 1] * itp) +
             T2 * itf * (t3val[p * 3 + 2] * itp);
  float fs = (cposG[i] / 360.0f + cnegG[i] / 360.0f) * 0.5f;
  diag[i] = fs + 0.25f * (s2 * 0.12247448713915890f);  // sqrt(3/200)
}

// -------------------- 4. graphs scatter (global atomics, scale folded) -----
__global__ __launch_bounds__(256) void k_graphs_scatter(
    const float* __restrict__ diag, const int* __restrict__ t3idx,
    const float* __restrict__ t3sign, float* __restrict__ gout) {
  const int i = blockIdx.x * 256 + threadIdx.x;
  if (i >= kB * kP) return;
  const int b = i / kP, p = i % kP;
  const float d = diag[i];
  int   ii[3];
  float rr[3];
#pragma unroll
  for (int j = 0; j < 3; ++j) {
    ii[j] = t3idx[p * 3 + j];
    rr[j] = t3sign[p * 3 + j] * (1.0f / 3.0f);
  }
  float* go = gout + (size_t)b * kN * kN;
#pragma unroll
  for (int j = 0; j < 3; ++j)
#pragma unroll
    for (int k = 0; k < 3; ++k) {
      float nd = (ii[j] == ii[k]) ? 1.0f : 3.0f;  // non_diag, /0.6 folded
      atomicAdd(&go[ii[j] * kN + ii[k]], d * rr[j] * rr[k] * nd * (1.0f / 0.6f));
    }
}

// -------------------- 5. classifier: h=relu(g@W1+b1), partial mean ---------
__global__ __launch_bounds__(256) void k_classifier(
    const float* __restrict__ graphs, const float* __restrict__ W1,
    const float* __restrict__ b1, float* __restrict__ meanh) {
  const int b = blockIdx.x / 8, nc = blockIdx.x % 8;
  const int tid = threadIdx.x;
  __shared__ float g[25][kN];
  for (int i = tid; i < 25 * kN; i += 256) {
    int n = i / kN, m = i % kN;
    g[n][m] = graphs[(size_t)b * kN * kN + (size_t)(nc * 25 + n) * kN + m];
  }
  __syncthreads();
  const int hh = tid & 127, grp = tid >> 7;  // 0/1
  const int ns = (grp == 0) ? 0 : 13, ne = (grp == 0) ? 13 : 25;
  float sumh = 0.f;
  for (int n = ns; n < ne; ++n) {
    float acc = b1[hh];
    for (int m = 0; m < kN; ++m) acc = fmaf(g[n][m], W1[m * kH + hh], acc);
    sumh += fmaxf(acc, 0.f);
  }
  atomicAdd(&meanh[b * kH + hh], sumh);
}

// -------------------- 6. head: out = mean_h @ W2 + b2, and norm ------------
__global__ __launch_bounds__(64) void k_final(
    const float* __restrict__ meanh, const float* __restrict__ W2,
    const float* __restrict__ b2, const float* __restrict__ gsums,
    float* __restrict__ out) {
  const int tid = threadIdx.x;
  if (tid < 64) {
    int b = tid >> 1, k = tid & 1;
    float acc = 0.f;
    for (int h = 0; h < kH; ++h) {
      float mv = meanh[b * kH + h] / 200.0f;
      acc = fmaf(mv, W2[h * 2 + k], acc);
    }
    out[b * 2 + k] = acc + b2[k];
  }
  if (tid == 0) {
    float r = 1.0f - sqrtf(gsums[1]) / sqrtf(gsums[0]);
    out[64] = r * r;
  }
}

}  // namespace

extern "C" void kernel_launch(void* const* d_in, const int* in_sizes, int n_in,
                              void* d_out, int out_size, void* d_ws, size_t ws_size,
                              hipStream_t stream) {
  const float* x   = (const float*)d_in[0];
  // d_in[1] = length (always 9000; shapes static)
  const float* pat = (const float*)d_in[2];
  const float* W1  = (const float*)d_in[3];
  const float* b1  = (const float*)d_in[4];
  const float* W2  = (const float*)d_in[5];
  const float* b2  = (const float*)d_in[6];
  float* out = (float*)d_out;

  char* ws = (char*)d_ws;
  float* gsums  = (float*)(ws + 0);
  float* meanh  = (float*)(ws + 64);
  float* cpos   = (float*)(ws + 16448);
  float* cneg   = (float*)(ws + 42048);
  float* asum   = (float*)(ws + 67648);
  float* diag   = (float*)(ws + 144448);
  float* ssqtp  = (float*)(ws + 170048);
  float* t3val  = (float*)(ws + 170848);
  float* t3sign = (float*)(ws + 173248);
  int*   t3idx  = (int*)(ws + 175648);
  float* npm    = (float*)(ws + 178048);

  // zero all accumulator regions: gsums+meanh+cpos+cneg+asum
  hipMemsetAsync(d_ws, 0, 144448, stream);
  // zero graphs output region (built via atomics)
  hipMemsetAsync((char*)d_out + 65 * 4, 0, (size_t)kB * kN * kN * 4, stream);

  k_pattern<<<kP, 64, 0, stream>>>(pat, npm, t3val, t3idx, t3sign, ssqtp, gsums);
  k_scores_fused<<<kB * 72, 512, 0, stream>>>(x, npm, t3idx, asum, cpos, cneg);
  k_diag<<<(kB * kP + 255) / 256, 256, 0, stream>>>(asum, cpos, cneg, t3val,
                                                    ssqtp, diag);
  k_graphs_scatter<<<(kB * kP + 255) / 256, 256, 0, stream>>>(diag, t3idx, t3sign,
                                                              out + 65);
  k_classifier<<<kB * 8, 256, 0, stream>>>(out + 65, W1, b1, meanh);
  k_final<<<1, 64, 0, stream>>>(meanh, W2, b2, gsums, out);
}